// Round 1
// baseline (1842.875 us; speedup 1.0000x reference)
//
#include <hip/hip_runtime.h>
#include <hip/hip_bf16.h>

// CktGNN encoder. B=4096 independent graphs, 10 sequential GRU steps each.
// Strategy: block owns BT=8 graphs end-to-end (no inter-block sync).
//   - gated[u] computed once per vertex, cached bf16 in LDS
//   - one-hot GRU input => 2 column lookups instead of 35-dot
//   - weights pre-transposed into d_ws for coalesced lane-contiguous reads

#define HS 301
#define NVT 26
#define MAXPOS 9
#define MAXN 10
#define BSZ 4096
#define XDIM 35
#define G3 903   // 3*HS
#define VS 310   // HS + MAXPOS
#define GS 309   // HS + FEAT
#define NZ 56

__device__ __forceinline__ unsigned short f2bf(float f) {
  unsigned int u = __float_as_uint(f);
  unsigned int r = (u + 0x7FFFu + ((u >> 16) & 1u)) >> 16;  // RNE
  return (unsigned short)r;
}
__device__ __forceinline__ float bf2f(unsigned short s) {
  return __uint_as_float(((unsigned int)s) << 16);
}
__device__ __forceinline__ float sigmoidf(float x) {
  return 1.0f / (1.0f + __expf(-x));
}

constexpr int BT  = 8;
constexpr int NTH = 320;

// ---------------- prep: transpose weights into ws ----------------
__global__ void ckt_prep(const float* __restrict__ Wih, const float* __restrict__ Whh,
                         const float* __restrict__ Wg,  const float* __restrict__ Wm,
                         const float* __restrict__ Wmu, const float* __restrict__ Wlv,
                         float* __restrict__ ws)
{
  float* WhhT = ws;                 // [HS][G3]
  float* WgT  = WhhT + HS * G3;     // [VS][HS]
  float* WmT  = WgT  + VS * HS;     // [VS][HS]
  float* WihT = WmT  + VS * HS;     // [XDIM][G3]
  float* WmuT = WihT + XDIM * G3;   // [GS][NZ]
  float* WlvT = WmuT + GS * NZ;     // [GS][NZ]
  int stride = gridDim.x * blockDim.x;
  int i0 = blockIdx.x * blockDim.x + threadIdx.x;
  for (int i = i0; i < HS * G3; i += stride) {
    int k = i / G3, j = i % G3;
    WhhT[i] = Whh[j * HS + k];
  }
  for (int i = i0; i < VS * HS; i += stride) {
    int k = i / HS, j = i % HS;
    WgT[i] = Wg[j * VS + k];
    WmT[i] = Wm[j * VS + k];
  }
  for (int i = i0; i < XDIM * G3; i += stride) {
    int k = i / G3, j = i % G3;
    WihT[i] = Wih[j * XDIM + k];
  }
  for (int i = i0; i < GS * NZ; i += stride) {
    int k = i / NZ, o = i % NZ;
    WmuT[i] = Wmu[o * GS + k];
    WlvT[i] = Wlv[o * GS + k];
  }
}

// ---------------- main ----------------
__global__ __launch_bounds__(NTH, 2) void ckt_main(
    const int* __restrict__ node_type, const int* __restrict__ pos,
    const int* __restrict__ adj, const int* __restrict__ vcount,
    const float* __restrict__ rin, const float* __restrict__ cin,
    const float* __restrict__ gmin,
    const float* __restrict__ b_ih, const float* __restrict__ b_hh,
    const float* __restrict__ bg,
    const float* __restrict__ W1, const float* __restrict__ b1,
    const float* __restrict__ W2, const float* __restrict__ b2,
    const float* __restrict__ bmu, const float* __restrict__ blv,
    const float* __restrict__ WhhT, const float* __restrict__ WgT,
    const float* __restrict__ WmT,  const float* __restrict__ WihT,
    const float* __restrict__ WmuT, const float* __restrict__ WlvT,
    float* __restrict__ out)
{
  __shared__ unsigned short s_gated[BT][MAXN][302];  // bf16 gated history
  __shared__ float s_h[BT][304];                     // Hin / GRU h
  __shared__ float s_H[BT][304];                     // current H[v]
  __shared__ unsigned short s_Hg[BT][304];           // graph state (bf16)
  __shared__ float s_A[BT][MAXN][MAXN];
  __shared__ int   s_t[BT][MAXN];
  __shared__ int   s_p[BT][MAXN];
  __shared__ int   s_n[BT];
  __shared__ float s_df[BT][28];
  __shared__ float s_hd[BT][16];
  __shared__ float s_hd2[BT][8];

  const int tid = threadIdx.x;
  const int b0  = blockIdx.x * BT;

  if (tid < BT) {
    int n = vcount[b0 + tid];
    n = n < 1 ? 1 : (n > MAXN ? MAXN : n);
    s_n[tid] = n;
  }
  if (tid < BT * MAXN) {
    int bb = tid / MAXN, v = tid % MAXN;
    s_t[bb][v] = node_type[(b0 + bb) * MAXN + v];
    s_p[bb][v] = pos[(b0 + bb) * MAXN + v];
  }
  __syncthreads();
  for (int i = tid; i < BT * MAXN * MAXN; i += NTH) {
    int bb = i / 100;
    int uv = i % 100;
    int u = uv / 10, v = uv % 10;
    float a = 0.f;
    if (u < v && v < s_n[bb]) a = (float)adj[(b0 + bb) * 100 + uv];
    s_A[bb][u][v] = a;
  }
  __syncthreads();

  const int j = tid;

  for (int v = 0; v < MAXN; ++v) {
    // ---- Hin[v] = sum_{u<v} A[u][v] * gated[u] ----
    if (j < HS) {
      for (int bb = 0; bb < BT; ++bb) {
        float acc = 0.f;
        for (int u = 0; u < v; ++u) {
          float a = s_A[bb][u][v];           // wave-uniform
          if (a != 0.f) acc += a * bf2f(s_gated[bb][u][j]);
        }
        s_h[bb][j] = acc;
      }
    }
    __syncthreads();

    // ---- GRU: H[v] = GRUCell(X[v], Hin) ----
    if (j < HS) {
      float hr[BT], hz[BT], hn[BT];
      #pragma unroll
      for (int bb = 0; bb < BT; ++bb) { hr[bb] = 0.f; hz[bb] = 0.f; hn[bb] = 0.f; }
      const float* Wp = WhhT + j;
      #pragma unroll 2
      for (int k = 0; k < HS; ++k) {
        float wr = Wp[k * G3];
        float wz = Wp[k * G3 + HS];
        float wn = Wp[k * G3 + 2 * HS];
        #pragma unroll
        for (int bb = 0; bb < BT; ++bb) {
          float hk = s_h[bb][k];
          hr[bb] = fmaf(wr, hk, hr[bb]);
          hz[bb] = fmaf(wz, hk, hz[bb]);
          hn[bb] = fmaf(wn, hk, hn[bb]);
        }
      }
      float bihr = b_ih[j], bihz = b_ih[HS + j], bihn = b_ih[2 * HS + j];
      float bhhr = b_hh[j], bhhz = b_hh[HS + j], bhhn = b_hh[2 * HS + j];
      #pragma unroll
      for (int bb = 0; bb < BT; ++bb) {
        int t = s_t[bb][v], p = s_p[bb][v];
        float ir  = bihr + WihT[t * G3 + j]            + WihT[(NVT + p) * G3 + j];
        float iz  = bihz + WihT[t * G3 + HS + j]       + WihT[(NVT + p) * G3 + HS + j];
        float in_ = bihn + WihT[t * G3 + 2 * HS + j]   + WihT[(NVT + p) * G3 + 2 * HS + j];
        float rg = sigmoidf(ir + bhhr + hr[bb]);
        float zg = sigmoidf(iz + bhhz + hz[bb]);
        float ng = tanhf(in_ + rg * (bhhn + hn[bb]));
        float h  = s_h[bb][j];
        float hv = (1.f - zg) * ng + zg * h;
        bool val = v < s_n[bb];
        s_H[bb][j] = val ? hv : 0.f;
        if (v == s_n[bb] - 1) s_Hg[bb][j] = f2bf(hv);  // Hg = H[n-1]
      }
    }
    __syncthreads();

    // ---- gated[v] = sigmoid(Wg·(H_v||p_v)+bg) * (Wm·(H_v||p_v)) ----
    if (j < HS) {
      float ga[BT], ma[BT];
      #pragma unroll
      for (int bb = 0; bb < BT; ++bb) { ga[bb] = 0.f; ma[bb] = 0.f; }
      const float* Wgp = WgT + j;
      const float* Wmp = WmT + j;
      #pragma unroll 2
      for (int k = 0; k < HS; ++k) {
        float wg = Wgp[k * HS];
        float wm = Wmp[k * HS];
        #pragma unroll
        for (int bb = 0; bb < BT; ++bb) {
          float hk = s_H[bb][k];
          ga[bb] = fmaf(wg, hk, ga[bb]);
          ma[bb] = fmaf(wm, hk, ma[bb]);
        }
      }
      float bgj = bg[j];
      #pragma unroll
      for (int bb = 0; bb < BT; ++bb) {
        int p = s_p[bb][v];
        float g = sigmoidf(ga[bb] + WgT[(HS + p) * HS + j] + bgj);
        float m = ma[bb] + WmT[(HS + p) * HS + j];
        s_gated[bb][v][j] = f2bf(g * m);
      }
    }
    __syncthreads();
  }

  // ---- df feature (sequential overwrite per graph) ----
  if (tid < BT) {
    int bb = tid;
    #pragma unroll
    for (int i2 = 0; i2 < 27; ++i2) s_df[bb][i2] = 0.f;
    int n = s_n[bb];
    for (int v = 0; v < n; ++v) {
      int p = s_p[bb][v];
      int base = (b0 + bb) * MAXN + v;
      s_df[bb][3 * p]     = rin[base];
      s_df[bb][3 * p + 1] = cin[base];
      s_df[bb][3 * p + 2] = gmin[base];
    }
  }
  __syncthreads();

  // ---- df_enc ----
  if (tid < BT * 16) {
    int bb = tid >> 4, o = tid & 15;
    float a = b1[o];
    #pragma unroll
    for (int k = 0; k < 27; ++k) a = fmaf(W1[o * 27 + k], s_df[bb][k], a);
    s_hd[bb][o] = fmaxf(a, 0.f);
  }
  __syncthreads();
  if (tid < BT * 8) {
    int bb = tid >> 3, o = tid & 7;
    float a = b2[o];
    #pragma unroll
    for (int k = 0; k < 16; ++k) a = fmaf(W2[o * 16 + k], s_hd[bb][k], a);
    s_hd2[bb][o] = a;
  }
  __syncthreads();

  // ---- heads: mu / logvar ----
  for (int o = tid; o < 2 * NZ; o += NTH) {
    bool ismu = o < NZ;
    int oo = ismu ? o : o - NZ;
    const float* WT = ismu ? WmuT : WlvT;
    float acc[BT];
    #pragma unroll
    for (int bb = 0; bb < BT; ++bb) acc[bb] = 0.f;
    for (int k = 0; k < HS; ++k) {
      float w = WT[k * NZ + oo];
      #pragma unroll
      for (int bb = 0; bb < BT; ++bb) acc[bb] = fmaf(w, bf2f(s_Hg[bb][k]), acc[bb]);
    }
    #pragma unroll
    for (int kk = 0; kk < 8; ++kk) {
      float w = WT[(HS + kk) * NZ + oo];
      #pragma unroll
      for (int bb = 0; bb < BT; ++bb) acc[bb] = fmaf(w, s_hd2[bb][kk], acc[bb]);
    }
    float bias = ismu ? bmu[oo] : blv[oo];
    for (int bb = 0; bb < BT; ++bb) {
      out[(ismu ? 0 : BSZ * NZ) + (b0 + bb) * NZ + oo] = acc[bb] + bias;
    }
  }
}

extern "C" void kernel_launch(void* const* d_in, const int* in_sizes, int n_in,
                              void* d_out, int out_size, void* d_ws, size_t ws_size,
                              hipStream_t stream) {
  const int*   node_type = (const int*)d_in[0];
  const int*   pos       = (const int*)d_in[1];
  const int*   adj       = (const int*)d_in[2];
  const int*   vcount    = (const int*)d_in[3];
  const float* rin       = (const float*)d_in[4];
  const float* cin       = (const float*)d_in[5];
  const float* gmin      = (const float*)d_in[6];
  const float* Wih       = (const float*)d_in[7];
  const float* Whh       = (const float*)d_in[8];
  const float* b_ih      = (const float*)d_in[9];
  const float* b_hh      = (const float*)d_in[10];
  const float* Wg        = (const float*)d_in[11];
  const float* bg        = (const float*)d_in[12];
  const float* Wm        = (const float*)d_in[13];
  const float* W1        = (const float*)d_in[14];
  const float* b1        = (const float*)d_in[15];
  const float* W2        = (const float*)d_in[16];
  const float* b2        = (const float*)d_in[17];
  const float* Wmu       = (const float*)d_in[18];
  const float* bmu       = (const float*)d_in[19];
  const float* Wlv       = (const float*)d_in[20];
  const float* blv       = (const float*)d_in[21];

  float* ws = (float*)d_ws;  // needs ~2.1 MB
  ckt_prep<<<512, 256, 0, stream>>>(Wih, Whh, Wg, Wm, Wmu, Wlv, ws);

  const float* WhhT = ws;
  const float* WgT  = WhhT + HS * G3;
  const float* WmT  = WgT  + VS * HS;
  const float* WihT = WmT  + VS * HS;
  const float* WmuT = WihT + XDIM * G3;
  const float* WlvT = WmuT + GS * NZ;

  ckt_main<<<BSZ / BT, NTH, 0, stream>>>(node_type, pos, adj, vcount, rin, cin, gmin,
      b_ih, b_hh, bg, W1, b1, W2, b2, bmu, blv,
      WhhT, WgT, WmT, WihT, WmuT, WlvT, (float*)d_out);
}

// Round 2
// 984.281 us; speedup vs baseline: 1.8723x; 1.8723x over previous
//
#include <hip/hip_runtime.h>
#include <hip/hip_bf16.h>

// CktGNN encoder. B=4096 independent graphs, 10 sequential GRU steps each.
// Round 2: latency/occupancy fix.
//   - BT=4 graphs/block, 1024 blocks -> 4 blocks/CU (LDS ~37 KB)
//   - all matvec weights packed f16 pairs; inner products via v_dot2_f32_f16
//   - h/H/gated stored f16 in LDS (pair-readable as uint)
//   - Hin kept in registers between phases

#define HS 301
#define NVT 26
#define MAXPOS 9
#define MAXN 10
#define BSZ 4096
#define G3 903   // 3*HS
#define VS 310   // HS + MAXPOS
#define GS 309   // HS + FEAT
#define NZ 56
#define KK 151   // ceil(HS/2) packed-pair count

typedef _Float16 h2v __attribute__((ext_vector_type(2)));

__device__ __forceinline__ float dot2f(unsigned int w, unsigned int h, float acc) {
#if __has_builtin(__builtin_amdgcn_fdot2)
  return __builtin_amdgcn_fdot2(__builtin_bit_cast(h2v, w),
                                __builtin_bit_cast(h2v, h), acc, false);
#else
  h2v a = __builtin_bit_cast(h2v, w), b = __builtin_bit_cast(h2v, h);
  acc = fmaf((float)a[0], (float)b[0], acc);
  return fmaf((float)a[1], (float)b[1], acc);
#endif
}

__device__ __forceinline__ float sigmoidf(float x) {
  return 1.0f / (1.0f + __expf(-x));
}

constexpr int BT  = 4;
constexpr int NTH = 320;

// ---------------- prep: transpose + f16-pack weights into ws ----------------
__global__ void ckt_prep(const float* __restrict__ Wih, const float* __restrict__ Whh,
                         const float* __restrict__ Wg,  const float* __restrict__ Wm,
                         const float* __restrict__ Wmu, const float* __restrict__ Wlv,
                         unsigned int* __restrict__ WhhP, unsigned int* __restrict__ WgmP,
                         float* __restrict__ WposG, float* __restrict__ WposM,
                         float* __restrict__ WihT, float* __restrict__ WmuT,
                         float* __restrict__ WlvT)
{
  int i0 = blockIdx.x * blockDim.x + threadIdx.x;
  int stride = gridDim.x * blockDim.x;
  // WhhP: [KK][G3] packed pairs (k,k+1) of Whh col-major
  for (int i = i0; i < KK * G3; i += stride) {
    int kk = i / G3, c = i % G3;
    float lo = Whh[c * HS + 2 * kk];
    float hi = (2 * kk + 1 < HS) ? Whh[c * HS + 2 * kk + 1] : 0.f;
    h2v p; p[0] = (_Float16)lo; p[1] = (_Float16)hi;
    WhhP[i] = __builtin_bit_cast(unsigned int, p);
  }
  // WgmP: [KK][602] cols 0..300 = Wg (H part), 301..601 = Wm (H part)
  for (int i = i0; i < KK * 602; i += stride) {
    int kk = i / 602, c = i % 602;
    const float* W = (c < HS) ? Wg : Wm;
    int jj = (c < HS) ? c : c - HS;
    float lo = W[jj * VS + 2 * kk];
    float hi = (2 * kk + 1 < HS) ? W[jj * VS + 2 * kk + 1] : 0.f;
    h2v p; p[0] = (_Float16)lo; p[1] = (_Float16)hi;
    WgmP[i] = __builtin_bit_cast(unsigned int, p);
  }
  // pos one-hot columns of Wg/Wm (fp32)
  for (int i = i0; i < MAXPOS * HS; i += stride) {
    int p = i / HS, jj = i % HS;
    WposG[i] = Wg[jj * VS + HS + p];
    WposM[i] = Wm[jj * VS + HS + p];
  }
  // WihT: [XDIM=35][G3] fp32
  for (int i = i0; i < 35 * G3; i += stride) {
    int k = i / G3, jj = i % G3;
    WihT[i] = Wih[jj * 35 + k];
  }
  // heads transposed fp32
  for (int i = i0; i < GS * NZ; i += stride) {
    int k = i / NZ, o = i % NZ;
    WmuT[i] = Wmu[o * GS + k];
    WlvT[i] = Wlv[o * GS + k];
  }
}

// ---------------- main ----------------
__global__ __launch_bounds__(NTH, 4) void ckt_main(
    const int* __restrict__ node_type, const int* __restrict__ pos,
    const int* __restrict__ adj, const int* __restrict__ vcount,
    const float* __restrict__ rin, const float* __restrict__ cin,
    const float* __restrict__ gmin,
    const float* __restrict__ b_ih, const float* __restrict__ b_hh,
    const float* __restrict__ bg,
    const float* __restrict__ W1, const float* __restrict__ b1,
    const float* __restrict__ W2, const float* __restrict__ b2,
    const float* __restrict__ bmu, const float* __restrict__ blv,
    const unsigned int* __restrict__ WhhP, const unsigned int* __restrict__ WgmP,
    const float* __restrict__ WposG, const float* __restrict__ WposM,
    const float* __restrict__ WihT,
    const float* __restrict__ WmuT, const float* __restrict__ WlvT,
    float* __restrict__ out)
{
  __shared__ _Float16 s_g[BT][MAXN][302];  // gated history (f16)
  __shared__ _Float16 s_h[BT][304];        // Hin (f16, pair-readable)
  __shared__ _Float16 s_H[BT][304];        // current H[v] (f16, pair-readable)
  __shared__ float    s_Hg[BT][302];       // graph state (fp32)
  __shared__ float    s_A[BT][MAXN][MAXN];
  __shared__ int      s_t[BT][MAXN];
  __shared__ int      s_p[BT][MAXN];
  __shared__ int      s_n[BT];
  __shared__ float    s_df[BT][28];
  __shared__ float    s_hd[BT][16];
  __shared__ float    s_hd2[BT][8];

  const int tid = threadIdx.x;
  const int b0  = blockIdx.x * BT;
  const int j   = tid;

  if (tid < BT) {
    int n = vcount[b0 + tid];
    n = n < 1 ? 1 : (n > MAXN ? MAXN : n);
    s_n[tid] = n;
    // zero the f16 pair-padding (never rewritten: only j<HS written per step)
    s_h[tid][301] = (_Float16)0.f; s_h[tid][302] = (_Float16)0.f; s_h[tid][303] = (_Float16)0.f;
    s_H[tid][301] = (_Float16)0.f; s_H[tid][302] = (_Float16)0.f; s_H[tid][303] = (_Float16)0.f;
  }
  if (tid < BT * MAXN) {
    int bb = tid / MAXN, v = tid % MAXN;
    s_t[bb][v] = node_type[(b0 + bb) * MAXN + v];
    s_p[bb][v] = pos[(b0 + bb) * MAXN + v];
  }
  __syncthreads();
  for (int i = tid; i < BT * MAXN * MAXN; i += NTH) {
    int bb = i / 100;
    int uv = i % 100;
    int u = uv / 10, vv = uv % 10;
    float a = 0.f;
    if (u < vv && vv < s_n[bb]) a = (float)adj[(b0 + bb) * 100 + uv];
    s_A[bb][u][vv] = a;
  }
  __syncthreads();

  float hin[BT];

  for (int v = 0; v < MAXN; ++v) {
    // ---- phase A: Hin[v] = sum_{u<v} A[u][v] * gated[u] (A is 0/1) ----
    if (j < HS) {
      #pragma unroll
      for (int bb = 0; bb < BT; ++bb) {
        float acc = 0.f;
        for (int u = 0; u < v; ++u) {
          float a = s_A[bb][u][v];           // wave-uniform
          if (a != 0.f) acc += (float)s_g[bb][u][j];
        }
        hin[bb] = acc;
        s_h[bb][j] = (_Float16)acc;
      }
    }
    __syncthreads();

    // ---- phase B: GRU ----
    if (j < HS) {
      float ar[BT], az[BT], an[BT];
      #pragma unroll
      for (int bb = 0; bb < BT; ++bb) { ar[bb] = 0.f; az[bb] = 0.f; an[bb] = 0.f; }
      const unsigned int* hP = (const unsigned int*)&s_h[0][0];  // bb stride 152
      #pragma unroll 2
      for (int kk = 0; kk < KK; ++kk) {
        unsigned int wr = WhhP[kk * G3 + j];
        unsigned int wz = WhhP[kk * G3 + HS + j];
        unsigned int wn = WhhP[kk * G3 + 2 * HS + j];
        #pragma unroll
        for (int bb = 0; bb < BT; ++bb) {
          unsigned int hh = hP[bb * 152 + kk];                  // broadcast
          ar[bb] = dot2f(wr, hh, ar[bb]);
          az[bb] = dot2f(wz, hh, az[bb]);
          an[bb] = dot2f(wn, hh, an[bb]);
        }
      }
      float bihr = b_ih[j], bihz = b_ih[HS + j], bihn = b_ih[2 * HS + j];
      float bhhr = b_hh[j], bhhz = b_hh[HS + j], bhhn = b_hh[2 * HS + j];
      #pragma unroll
      for (int bb = 0; bb < BT; ++bb) {
        int t = s_t[bb][v], p = s_p[bb][v];
        const float* c1 = WihT + t * G3 + j;
        const float* c2 = WihT + (NVT + p) * G3 + j;
        float ir  = bihr + c1[0]      + c2[0];
        float iz  = bihz + c1[HS]     + c2[HS];
        float in_ = bihn + c1[2 * HS] + c2[2 * HS];
        float rg = sigmoidf(ir + bhhr + ar[bb]);
        float zg = sigmoidf(iz + bhhz + az[bb]);
        float ng = tanhf(in_ + rg * (bhhn + an[bb]));
        float hv = (1.f - zg) * ng + zg * hin[bb];
        bool val = v < s_n[bb];
        s_H[bb][j] = val ? (_Float16)hv : (_Float16)0.f;
        if (v == s_n[bb] - 1) s_Hg[bb][j] = hv;   // v = n-1 is always valid
      }
    }
    __syncthreads();

    // ---- phase C: gated[v] = sigmoid(Wg.(H||p)+bg) * (Wm.(H||p)) ----
    if (j < HS) {
      float ag[BT], am[BT];
      #pragma unroll
      for (int bb = 0; bb < BT; ++bb) { ag[bb] = 0.f; am[bb] = 0.f; }
      const unsigned int* HP = (const unsigned int*)&s_H[0][0];
      #pragma unroll 2
      for (int kk = 0; kk < KK; ++kk) {
        unsigned int wg = WgmP[kk * 602 + j];
        unsigned int wm = WgmP[kk * 602 + HS + j];
        #pragma unroll
        for (int bb = 0; bb < BT; ++bb) {
          unsigned int hh = HP[bb * 152 + kk];
          ag[bb] = dot2f(wg, hh, ag[bb]);
          am[bb] = dot2f(wm, hh, am[bb]);
        }
      }
      float bgj = bg[j];
      #pragma unroll
      for (int bb = 0; bb < BT; ++bb) {
        int p = s_p[bb][v];
        float g = sigmoidf(ag[bb] + WposG[p * HS + j] + bgj);
        float m = am[bb] + WposM[p * HS + j];
        s_g[bb][v][j] = (_Float16)(g * m);
      }
    }
    __syncthreads();
  }

  // ---- df feature (sequential overwrite per graph) ----
  if (tid < BT) {
    int bb = tid;
    #pragma unroll
    for (int i2 = 0; i2 < 27; ++i2) s_df[bb][i2] = 0.f;
    int n = s_n[bb];
    for (int v = 0; v < n; ++v) {
      int p = s_p[bb][v];
      int base = (b0 + bb) * MAXN + v;
      s_df[bb][3 * p]     = rin[base];
      s_df[bb][3 * p + 1] = cin[base];
      s_df[bb][3 * p + 2] = gmin[base];
    }
  }
  __syncthreads();

  // ---- df_enc ----
  if (tid < BT * 16) {
    int bb = tid >> 4, o = tid & 15;
    float a = b1[o];
    #pragma unroll
    for (int k = 0; k < 27; ++k) a = fmaf(W1[o * 27 + k], s_df[bb][k], a);
    s_hd[bb][o] = fmaxf(a, 0.f);
  }
  __syncthreads();
  if (tid < BT * 8) {
    int bb = tid >> 3, o = tid & 7;
    float a = b2[o];
    #pragma unroll
    for (int k = 0; k < 16; ++k) a = fmaf(W2[o * 16 + k], s_hd[bb][k], a);
    s_hd2[bb][o] = a;
  }
  __syncthreads();

  // ---- heads: mu / logvar ----
  for (int o = tid; o < 2 * NZ; o += NTH) {
    bool ismu = o < NZ;
    int oo = ismu ? o : o - NZ;
    const float* WT = ismu ? WmuT : WlvT;
    float acc[BT];
    #pragma unroll
    for (int bb = 0; bb < BT; ++bb) acc[bb] = 0.f;
    for (int k = 0; k < HS; ++k) {
      float w = WT[k * NZ + oo];
      #pragma unroll
      for (int bb = 0; bb < BT; ++bb) acc[bb] = fmaf(w, s_Hg[bb][k], acc[bb]);
    }
    #pragma unroll
    for (int kk = 0; kk < 8; ++kk) {
      float w = WT[(HS + kk) * NZ + oo];
      #pragma unroll
      for (int bb = 0; bb < BT; ++bb) acc[bb] = fmaf(w, s_hd2[bb][kk], acc[bb]);
    }
    float bias = ismu ? bmu[oo] : blv[oo];
    for (int bb = 0; bb < BT; ++bb) {
      out[(ismu ? 0 : BSZ * NZ) + (b0 + bb) * NZ + oo] = acc[bb] + bias;
    }
  }
}

extern "C" void kernel_launch(void* const* d_in, const int* in_sizes, int n_in,
                              void* d_out, int out_size, void* d_ws, size_t ws_size,
                              hipStream_t stream) {
  const int*   node_type = (const int*)d_in[0];
  const int*   pos       = (const int*)d_in[1];
  const int*   adj       = (const int*)d_in[2];
  const int*   vcount    = (const int*)d_in[3];
  const float* rin       = (const float*)d_in[4];
  const float* cin       = (const float*)d_in[5];
  const float* gmin      = (const float*)d_in[6];
  const float* Wih       = (const float*)d_in[7];
  const float* Whh       = (const float*)d_in[8];
  const float* b_ih      = (const float*)d_in[9];
  const float* b_hh      = (const float*)d_in[10];
  const float* Wg        = (const float*)d_in[11];
  const float* bg        = (const float*)d_in[12];
  const float* Wm        = (const float*)d_in[13];
  const float* W1        = (const float*)d_in[14];
  const float* b1        = (const float*)d_in[15];
  const float* W2        = (const float*)d_in[16];
  const float* b2        = (const float*)d_in[17];
  const float* Wmu       = (const float*)d_in[18];
  const float* bmu       = (const float*)d_in[19];
  const float* Wlv       = (const float*)d_in[20];
  const float* blv       = (const float*)d_in[21];

  // ws layout
  char* wsb = (char*)d_ws;
  unsigned int* WhhP = (unsigned int*)wsb;            wsb += (size_t)KK * G3 * 4;
  unsigned int* WgmP = (unsigned int*)wsb;            wsb += (size_t)KK * 602 * 4;
  float* WposG = (float*)wsb;                         wsb += (size_t)MAXPOS * HS * 4;
  float* WposM = (float*)wsb;                         wsb += (size_t)MAXPOS * HS * 4;
  float* WihT  = (float*)wsb;                         wsb += (size_t)35 * G3 * 4;
  float* WmuT  = (float*)wsb;                         wsb += (size_t)GS * NZ * 4;
  float* WlvT  = (float*)wsb;                         wsb += (size_t)GS * NZ * 4;

  ckt_prep<<<256, 256, 0, stream>>>(Wih, Whh, Wg, Wm, Wmu, Wlv,
                                    WhhP, WgmP, WposG, WposM, WihT, WmuT, WlvT);

  ckt_main<<<BSZ / BT, NTH, 0, stream>>>(node_type, pos, adj, vcount, rin, cin, gmin,
      b_ih, b_hh, bg, W1, b1, W2, b2, bmu, blv,
      WhhP, WgmP, WposG, WposM, WihT, WmuT, WlvT, (float*)d_out);
}

// Round 4
// 811.893 us; speedup vs baseline: 2.2699x; 1.2123x over previous
//
#include <hip/hip_runtime.h>
#include <hip/hip_bf16.h>

// CktGNN encoder via MFMA. 256 blocks x 16 graphs (M=16), 4 waves each owning
// an 80-wide output-column slice. Weights pre-packed into exact
// mfma_f32_16x16x32_f16 B-fragment order in ws (L2-resident, ~1.1 MB).
// One-hot inputs and biases folded into extended K:
//   GRU ext K=352: [Hin(301) | onehot_t(26) | onehot_p(9) | 1 | pad]
//   gate ext K=320: [H(301) | onehot_p(9) | 1 | pad]
// n-gate input part (needs separate inn) via fp32 table WnX in epilogue.
// R4 fix: gate one-hot fill was `if(tid<304)` with NTH=256 -> graphs 14/15
// never initialized (absmax 2.16). Now a strided loop. Also zero sHg pad.

#define HS 301
#define NVT 26
#define MAXPOS 9
#define MAXN 10
#define BSZ 4096
#define VS 310
#define GS 309
#define NZ 56

#define KT1 11          // GRU ext K tiles (K=352)
#define KT2 10          // gate ext K tiles (K=320)
#define NB1 (4*KT1*5*3*64*8)   // 337920 f16
#define NB2 (4*KT2*5*2*64*8)   // 204800 f16

typedef _Float16 f16x8 __attribute__((ext_vector_type(8)));
typedef float f32x4 __attribute__((ext_vector_type(4)));

constexpr int NTH = 256;
constexpr int BT  = 16;

__device__ __forceinline__ int fragOff(int g, int k) {
  // byte offset of element (row g, dim k) inside an A-fragment buffer
  return ((k >> 5) << 10) + ((((k & 31) >> 3) << 4) + g) * 16 + ((k & 7) << 1);
}
__device__ __forceinline__ float sigm(float x) { return 1.f / (1.f + __expf(-x)); }

// ---------------- prep: pack weights into fragment order ----------------
__global__ void ckt_prep(const float* __restrict__ Wih, const float* __restrict__ Whh,
                         const float* __restrict__ b_ih, const float* __restrict__ b_hh,
                         const float* __restrict__ Wg,  const float* __restrict__ bg,
                         const float* __restrict__ Wm,
                         const float* __restrict__ Wmu, const float* __restrict__ Wlv,
                         unsigned short* __restrict__ B1, unsigned short* __restrict__ B2,
                         float* __restrict__ WnX, float* __restrict__ bn,
                         float* __restrict__ WmuT, float* __restrict__ WlvT)
{
  int i0 = blockIdx.x * blockDim.x + threadIdx.x;
  int str = gridDim.x * blockDim.x;
  for (int i = i0; i < NB1; i += str) {
    int ii = i & 7, lane = (i >> 3) & 63;
    int r = i >> 9;
    int g3 = r % 3; r /= 3;
    int jt = r % 5; r /= 5;
    int kt = r % KT1; int w = r / KT1;
    int j = w * 80 + jt * 16 + (lane & 15);
    int k = kt * 32 + ((lane >> 4) << 3) + ii;
    float val = 0.f;
    if (j < HS) {
      int row = g3 * HS + j;
      if (k < HS) val = Whh[row * HS + k];
      else if (k == 336) val = (g3 < 2) ? (b_ih[row] + b_hh[row]) : b_hh[row];
      else if (g3 < 2) {
        if (k < 327)      val = Wih[row * 35 + (k - 301)];
        else if (k < 336) val = Wih[row * 35 + 26 + (k - 327)];
      }
    }
    B1[i] = __builtin_bit_cast(unsigned short, (_Float16)val);
  }
  for (int i = i0; i < NB2; i += str) {
    int ii = i & 7, lane = (i >> 3) & 63;
    int r = i >> 9;
    int gm = r & 1; r >>= 1;
    int jt = r % 5; r /= 5;
    int kt = r % KT2; int w = r / KT2;
    int j = w * 80 + jt * 16 + (lane & 15);
    int k = kt * 32 + ((lane >> 4) << 3) + ii;
    float val = 0.f;
    if (j < HS) {
      const float* W = gm ? Wm : Wg;
      if (k < HS)       val = W[j * VS + k];
      else if (k < 310) val = W[j * VS + HS + (k - 301)];
      else if (k == 310) val = gm ? 0.f : bg[j];
    }
    B2[i] = __builtin_bit_cast(unsigned short, (_Float16)val);
  }
  for (int i = i0; i < 35 * 320; i += str) {
    int x = i / 320, j = i % 320;
    WnX[i] = (j < HS) ? Wih[(2 * HS + j) * 35 + x] : 0.f;
  }
  for (int i = i0; i < 320; i += str) bn[i] = (i < HS) ? b_ih[2 * HS + i] : 0.f;
  for (int i = i0; i < GS * NZ; i += str) {
    int k = i / NZ, o = i % NZ;
    WmuT[i] = Wmu[o * GS + k];
    WlvT[i] = Wlv[o * GS + k];
  }
}

// ---------------- main ----------------
__global__ __launch_bounds__(NTH, 1) void ckt_main(
    const int* __restrict__ node_type, const int* __restrict__ pos,
    const int* __restrict__ adj, const int* __restrict__ vcount,
    const float* __restrict__ rin, const float* __restrict__ cin,
    const float* __restrict__ gmin,
    const float* __restrict__ W1, const float* __restrict__ b1,
    const float* __restrict__ W2, const float* __restrict__ b2,
    const float* __restrict__ bmu, const float* __restrict__ blv,
    const uint4* __restrict__ B1, const uint4* __restrict__ B2,
    const float* __restrict__ WnX, const float* __restrict__ bnG,
    const float* __restrict__ WmuT, const float* __restrict__ WlvT,
    float* __restrict__ out)
{
  __shared__ __align__(16) _Float16 sGhist[9 * 16 * 304];  // gated history, 87.5 KB
  __shared__ __align__(16) char sAf1[KT1 * 1024];          // GRU A-frags, 11 KB
  __shared__ __align__(16) char sAf2[KT2 * 1024];          // gate A-frags, 10 KB
  __shared__ __align__(16) _Float16 sHg[16 * 304];         // graph state, 9.5 KB
  __shared__ float sBn[320];
  __shared__ int s_t[160], s_p[160], s_n[16];
  __shared__ unsigned s_am[160];
  __shared__ float s_df[16][28];
  __shared__ float s_hd[16][16];
  __shared__ float s_hd2[16][8];

  const int tid  = threadIdx.x;
  const int b0   = blockIdx.x * BT;
  const int w    = tid >> 6;
  const int lane = tid & 63;

  if (tid < 16) {
    int n = vcount[b0 + tid];
    s_n[tid] = n < 1 ? 1 : (n > MAXN ? MAXN : n);
    // zero the f16 pad of sHg (read as part of f16x8 in heads; 0*garbage
    // would be fine unless garbage is NaN/Inf)
    sHg[tid * 304 + 301] = (_Float16)0.f;
    sHg[tid * 304 + 302] = (_Float16)0.f;
    sHg[tid * 304 + 303] = (_Float16)0.f;
  }
  if (tid < 160) {
    int g = tid / 10, vv = tid % 10;
    s_t[tid] = node_type[(b0 + g) * MAXN + vv];
    s_p[tid] = pos[(b0 + g) * MAXN + vv];
  }
  for (int k = tid; k < 320; k += NTH) sBn[k] = bnG[k];
  __syncthreads();
  if (tid < 160) {
    int g = tid / 10, vv = tid % 10;
    unsigned m = 0;
    if (vv < s_n[g]) {
      for (int u = 0; u < vv; ++u)
        if (adj[(b0 + g) * 100 + u * 10 + vv]) m |= (1u << u);
    }
    s_am[tid] = m;
  }
  __syncthreads();

  const int lq4 = (lane >> 4) << 2;   // base graph row of this lane's D rows
  const int jc  = lane & 15;          // column-within-tile

  for (int v = 0; v < MAXN; ++v) {
    // ---------- phase A: build GRU A-frags (Hin + one-hots) ----------
    for (int c = tid; c < KT1 * 64; c += NTH) {
      int kt = c >> 6, ln = c & 63, g = ln & 15;
      int k0 = (kt << 5) + ((ln >> 4) << 3);
      unsigned am = s_am[g * 10 + v];
      f16x8 pk;
      if (k0 + 8 <= HS) {               // pure Hin chunk
        float acc[8];
        #pragma unroll
        for (int e = 0; e < 8; ++e) acc[e] = 0.f;
        for (int u = 0; u < v; ++u) {
          float mf = (float)((am >> u) & 1u);
          f16x8 hh = *(const f16x8*)(sGhist + (u * 16 + g) * 304 + k0);
          #pragma unroll
          for (int e = 0; e < 8; ++e) acc[e] += mf * (float)hh[e];
        }
        #pragma unroll
        for (int e = 0; e < 8; ++e) pk[e] = (_Float16)acc[e];
      } else {                          // boundary / one-hot region
        int t = s_t[g * 10 + v], p = s_p[g * 10 + v];
        #pragma unroll
        for (int e = 0; e < 8; ++e) {
          int k = k0 + e;
          float x = 0.f;
          if (k < HS) {
            for (int u = 0; u < v; ++u)
              if ((am >> u) & 1u) x += (float)sGhist[(u * 16 + g) * 304 + k];
          } else if (k < 327) x = (k - 301 == t) ? 1.f : 0.f;
          else if (k < 336)   x = (k - 327 == p) ? 1.f : 0.f;
          else if (k == 336)  x = 1.f;
          pk[e] = (_Float16)x;
        }
      }
      *(f16x8*)(sAf1 + c * 16) = pk;
    }
    // gate A-frag one-hot region (k=301..319) for this vertex.
    // R4 FIX: 16*19=304 work items > NTH=256 -> must be a strided loop
    // (was `if (tid < 304)`, which left graphs 14/15 uninitialized).
    for (int i = tid; i < 16 * 19; i += NTH) {
      int g = i / 19, kk = 301 + i % 19;
      float val = (kk < 310) ? ((kk - 301 == s_p[g * 10 + v]) ? 1.f : 0.f)
                             : ((kk == 310) ? 1.f : 0.f);
      *(_Float16*)(sAf2 + fragOff(g, kk)) = (_Float16)val;
    }
    __syncthreads();

    // ---------- GRU GEMM: [16 x 352] x [352 x 240(per-wave 80x3)] ----------
    f32x4 acc[5][3];
    #pragma unroll
    for (int jt = 0; jt < 5; ++jt)
      #pragma unroll
      for (int g3 = 0; g3 < 3; ++g3) {
        f32x4 z = {0.f, 0.f, 0.f, 0.f};
        acc[jt][g3] = z;
      }
    #pragma unroll
    for (int kt = 0; kt < KT1; ++kt) {
      f16x8 av = *(const f16x8*)(sAf1 + kt * 1024 + lane * 16);
      #pragma unroll
      for (int jt = 0; jt < 5; ++jt)
        #pragma unroll
        for (int g3 = 0; g3 < 3; ++g3) {
          f16x8 bv = __builtin_bit_cast(f16x8,
              B1[((w * KT1 + kt) * 15 + jt * 3 + g3) * 64 + lane]);
          acc[jt][g3] = __builtin_amdgcn_mfma_f32_16x16x32_f16(av, bv, acc[jt][g3], 0, 0, 0);
        }
    }
    // GRU epilogue (in-register; D: row=graph=(lane>>4)*4+q, col=j=lane&15)
    #pragma unroll
    for (int jt = 0; jt < 5; ++jt) {
      int j = w * 80 + jt * 16 + jc;
      bool jv = j < HS;
      #pragma unroll
      for (int q = 0; q < 4; ++q) {
        int g = lq4 + q;
        float ar = acc[jt][0][q], az = acc[jt][1][q], an = acc[jt][2][q];
        float inn = 0.f;
        if (jv) {
          int t = s_t[g * 10 + v], p = s_p[g * 10 + v];
          inn = sBn[j] + WnX[t * 320 + j] + WnX[(26 + p) * 320 + j];
        }
        float rg = sigm(ar);
        float zg = sigm(az);
        float ng = tanhf(inn + rg * an);
        float hinv = (float)*(const _Float16*)(sAf1 + fragOff(g, j));  // Hin
        float hv = (1.f - zg) * ng + zg * hinv;
        float hval = (v < s_n[g]) ? hv : 0.f;
        if (jv) {
          *(_Float16*)(sAf2 + fragOff(g, j)) = (_Float16)hval;
          if (v == s_n[g] - 1) sHg[g * 304 + j] = (_Float16)hv;
        }
      }
    }
    __syncthreads();

    // ---------- gate/mapper GEMM: [16 x 320] x [320 x 160(per-wave 80x2)] ----------
    f32x4 acc2[5][2];
    #pragma unroll
    for (int jt = 0; jt < 5; ++jt)
      #pragma unroll
      for (int gm = 0; gm < 2; ++gm) {
        f32x4 z = {0.f, 0.f, 0.f, 0.f};
        acc2[jt][gm] = z;
      }
    #pragma unroll
    for (int kt = 0; kt < KT2; ++kt) {
      f16x8 av = *(const f16x8*)(sAf2 + kt * 1024 + lane * 16);
      #pragma unroll
      for (int jt = 0; jt < 5; ++jt)
        #pragma unroll
        for (int gm = 0; gm < 2; ++gm) {
          f16x8 bv = __builtin_bit_cast(f16x8,
              B2[((w * KT2 + kt) * 10 + jt * 2 + gm) * 64 + lane]);
          acc2[jt][gm] = __builtin_amdgcn_mfma_f32_16x16x32_f16(av, bv, acc2[jt][gm], 0, 0, 0);
        }
    }
    if (v < 9) {   // gated[9] never consumed
      #pragma unroll
      for (int jt = 0; jt < 5; ++jt) {
        int j = w * 80 + jt * 16 + jc;
        if (j < HS) {
          #pragma unroll
          for (int q = 0; q < 4; ++q) {
            int g = lq4 + q;
            float gg = sigm(acc2[jt][0][q]);
            sGhist[(v * 16 + g) * 304 + j] = (_Float16)(gg * acc2[jt][1][q]);
          }
        }
      }
    }
    __syncthreads();
  }

  // ---------- df feature ----------
  if (tid < 16) {
    int g = tid;
    #pragma unroll
    for (int i2 = 0; i2 < 27; ++i2) s_df[g][i2] = 0.f;
    int n = s_n[g];
    for (int vv = 0; vv < n; ++vv) {
      int p = s_p[g * 10 + vv];
      int base = (b0 + g) * MAXN + vv;
      s_df[g][3 * p]     = rin[base];
      s_df[g][3 * p + 1] = cin[base];
      s_df[g][3 * p + 2] = gmin[base];
    }
  }
  __syncthreads();

  // ---------- df_enc ----------
  {
    int bb = tid >> 4, o = tid & 15;   // 256 threads = 16x16
    float a = b1[o];
    #pragma unroll
    for (int k = 0; k < 27; ++k) a = fmaf(W1[o * 27 + k], s_df[bb][k], a);
    s_hd[bb][o] = fmaxf(a, 0.f);
  }
  __syncthreads();
  if (tid < 128) {
    int bb = tid >> 3, o = tid & 7;
    float a = b2[o];
    #pragma unroll
    for (int k = 0; k < 16; ++k) a = fmaf(W2[o * 16 + k], s_hd[bb][k], a);
    s_hd2[bb][o] = a;
  }
  __syncthreads();

  // ---------- heads ----------
  if (tid < 2 * NZ) {
    bool ismu = tid < NZ;
    int oo = ismu ? tid : tid - NZ;
    const float* WT = ismu ? WmuT : WlvT;
    float acc[16];
    #pragma unroll
    for (int g = 0; g < 16; ++g) acc[g] = 0.f;
    for (int k0 = 0; k0 < 304; k0 += 8) {
      float wv[8];
      #pragma unroll
      for (int e = 0; e < 8; ++e) {
        int k = k0 + e;
        wv[e] = (k < HS) ? WT[k * NZ + oo] : 0.f;
      }
      #pragma unroll
      for (int g = 0; g < 16; ++g) {
        f16x8 hh = *(const f16x8*)(sHg + g * 304 + k0);
        #pragma unroll
        for (int e = 0; e < 8; ++e) acc[g] += wv[e] * (float)hh[e];
      }
    }
    #pragma unroll
    for (int g = 0; g < 16; ++g) {
      float a = acc[g];
      #pragma unroll
      for (int kk = 0; kk < 8; ++kk) a += WT[(HS + kk) * NZ + oo] * s_hd2[g][kk];
      a += ismu ? bmu[oo] : blv[oo];
      out[(ismu ? 0 : BSZ * NZ) + (b0 + g) * NZ + oo] = a;
    }
  }
}

extern "C" void kernel_launch(void* const* d_in, const int* in_sizes, int n_in,
                              void* d_out, int out_size, void* d_ws, size_t ws_size,
                              hipStream_t stream) {
  const int*   node_type = (const int*)d_in[0];
  const int*   pos       = (const int*)d_in[1];
  const int*   adj       = (const int*)d_in[2];
  const int*   vcount    = (const int*)d_in[3];
  const float* rin       = (const float*)d_in[4];
  const float* cin       = (const float*)d_in[5];
  const float* gmin      = (const float*)d_in[6];
  const float* Wih       = (const float*)d_in[7];
  const float* Whh       = (const float*)d_in[8];
  const float* b_ih      = (const float*)d_in[9];
  const float* b_hh      = (const float*)d_in[10];
  const float* Wg        = (const float*)d_in[11];
  const float* bg        = (const float*)d_in[12];
  const float* Wm        = (const float*)d_in[13];
  const float* W1        = (const float*)d_in[14];
  const float* b1        = (const float*)d_in[15];
  const float* W2        = (const float*)d_in[16];
  const float* b2        = (const float*)d_in[17];
  const float* Wmu       = (const float*)d_in[18];
  const float* bmu       = (const float*)d_in[19];
  const float* Wlv       = (const float*)d_in[20];
  const float* blv       = (const float*)d_in[21];

  // ws layout (bytes, all 16B-aligned)
  char* wsb = (char*)d_ws;
  unsigned short* B1 = (unsigned short*)wsb;            // 675,840 B
  unsigned short* B2 = (unsigned short*)(wsb + 675840); // 409,600 B
  float* WnX  = (float*)(wsb + 1085440);                // 44,800 B
  float* bn   = (float*)(wsb + 1130240);                // 1,280 B
  float* WmuT = (float*)(wsb + 1131520);                // 69,216 B
  float* WlvT = (float*)(wsb + 1200736);                // 69,216 B

  ckt_prep<<<512, 256, 0, stream>>>(Wih, Whh, b_ih, b_hh, Wg, bg, Wm, Wmu, Wlv,
                                    B1, B2, WnX, bn, WmuT, WlvT);

  ckt_main<<<BSZ / BT, NTH, 0, stream>>>(node_type, pos, adj, vcount, rin, cin, gmin,
      W1, b1, W2, b2, bmu, blv,
      (const uint4*)B1, (const uint4*)B2, WnX, bn, WmuT, WlvT, (float*)d_out);
}

// Round 5
// 246.754 us; speedup vs baseline: 7.4685x; 3.2903x over previous
//
#include <hip/hip_runtime.h>
#include <hip/hip_bf16.h>

// CktGNN encoder via MFMA. 256 blocks x 16 graphs (M=16), NTH=1024 (16 waves).
// R5: fix R4's spill+latency disaster (VGPR=256, 186MB scratch writes, 11% occ):
//   - jt-OUTER loop: <=6 live f32x4 accumulators (was 25) -> no spills
//   - 16 waves/block, wave w owns j-tiles {w, w+16} of 19 -> 4 waves/SIMD
//   - B1/B2 packed [jt][kt][g3|gm] so each wave streams a contiguous slice
// Weights in exact mfma_f32_16x16x32_f16 B-fragment order (L2-resident ~1MB).
//   GRU ext K=352: [Hin(301) | onehot_t(26) | onehot_p(9) | 1 | pad]
//   gate ext K=320: [H(301) | onehot_p(9) | 1 | pad]

#define HS 301
#define NVT 26
#define MAXPOS 9
#define MAXN 10
#define BSZ 4096
#define VS 310
#define GS 309
#define NZ 56

#define KT1 11          // GRU ext K tiles (K=352)
#define KT2 10          // gate ext K tiles (K=320)
#define NJT 19          // j tiles (ceil(301/16) = 19, covers j<304)
#define NB1 (NJT*KT1*3*512)   // f16 count = 321024
#define NB2 (NJT*KT2*2*512)   // f16 count = 194560

typedef _Float16 f16x8 __attribute__((ext_vector_type(8)));
typedef float f32x4 __attribute__((ext_vector_type(4)));

constexpr int NTH = 1024;
constexpr int BT  = 16;

__device__ __forceinline__ int fragOff(int g, int k) {
  // byte offset of element (row g, dim k) inside an A-fragment buffer
  return ((k >> 5) << 10) + ((((k & 31) >> 3) << 4) + g) * 16 + ((k & 7) << 1);
}
__device__ __forceinline__ float sigm(float x) { return 1.f / (1.f + __expf(-x)); }

// ---------------- prep: pack weights into fragment order ----------------
__global__ void ckt_prep(const float* __restrict__ Wih, const float* __restrict__ Whh,
                         const float* __restrict__ b_ih, const float* __restrict__ b_hh,
                         const float* __restrict__ Wg,  const float* __restrict__ bg,
                         const float* __restrict__ Wm,
                         const float* __restrict__ Wmu, const float* __restrict__ Wlv,
                         unsigned short* __restrict__ B1, unsigned short* __restrict__ B2,
                         float* __restrict__ WnX, float* __restrict__ bn,
                         float* __restrict__ WmuT, float* __restrict__ WlvT)
{
  int i0 = blockIdx.x * blockDim.x + threadIdx.x;
  int str = gridDim.x * blockDim.x;
  // B1: [jt][kt][g3][lane][ii]
  for (int i = i0; i < NB1; i += str) {
    int ii = i & 7, lane = (i >> 3) & 63;
    int r = i >> 9;
    int g3 = r % 3; r /= 3;
    int kt = r % KT1; int jt = r / KT1;
    int j = jt * 16 + (lane & 15);
    int k = kt * 32 + ((lane >> 4) << 3) + ii;
    float val = 0.f;
    if (j < HS) {
      int row = g3 * HS + j;
      if (k < HS) val = Whh[row * HS + k];
      else if (k == 336) val = (g3 < 2) ? (b_ih[row] + b_hh[row]) : b_hh[row];
      else if (g3 < 2) {
        if (k < 327)      val = Wih[row * 35 + (k - 301)];
        else if (k < 336) val = Wih[row * 35 + 26 + (k - 327)];
      }
    }
    B1[i] = __builtin_bit_cast(unsigned short, (_Float16)val);
  }
  // B2: [jt][kt][gm][lane][ii]
  for (int i = i0; i < NB2; i += str) {
    int ii = i & 7, lane = (i >> 3) & 63;
    int r = i >> 9;
    int gm = r % 2; r /= 2;
    int kt = r % KT2; int jt = r / KT2;
    int j = jt * 16 + (lane & 15);
    int k = kt * 32 + ((lane >> 4) << 3) + ii;
    float val = 0.f;
    if (j < HS) {
      const float* W = gm ? Wm : Wg;
      if (k < HS)       val = W[j * VS + k];
      else if (k < 310) val = W[j * VS + HS + (k - 301)];
      else if (k == 310) val = gm ? 0.f : bg[j];
    }
    B2[i] = __builtin_bit_cast(unsigned short, (_Float16)val);
  }
  for (int i = i0; i < 35 * 320; i += str) {
    int x = i / 320, j = i % 320;
    WnX[i] = (j < HS) ? Wih[(2 * HS + j) * 35 + x] : 0.f;
  }
  for (int i = i0; i < 320; i += str) bn[i] = (i < HS) ? b_ih[2 * HS + i] : 0.f;
  for (int i = i0; i < GS * NZ; i += str) {
    int k = i / NZ, o = i % NZ;
    WmuT[i] = Wmu[o * GS + k];
    WlvT[i] = Wlv[o * GS + k];
  }
}

// ---------------- main ----------------
__global__ __launch_bounds__(NTH, 4) void ckt_main(
    const int* __restrict__ node_type, const int* __restrict__ pos,
    const int* __restrict__ adj, const int* __restrict__ vcount,
    const float* __restrict__ rin, const float* __restrict__ cin,
    const float* __restrict__ gmin,
    const float* __restrict__ W1, const float* __restrict__ b1,
    const float* __restrict__ W2, const float* __restrict__ b2,
    const float* __restrict__ bmu, const float* __restrict__ blv,
    const uint4* __restrict__ B1, const uint4* __restrict__ B2,
    const float* __restrict__ WnX, const float* __restrict__ bnG,
    const float* __restrict__ WmuT, const float* __restrict__ WlvT,
    float* __restrict__ out)
{
  __shared__ __align__(16) _Float16 sGhist[9 * 16 * 304];  // gated history, 87.5 KB
  __shared__ __align__(16) char sAf1[KT1 * 1024];          // GRU A-frags, 11 KB
  __shared__ __align__(16) char sAf2[KT2 * 1024];          // gate A-frags, 10 KB
  __shared__ __align__(16) _Float16 sHg[16 * 304];         // graph state, 9.5 KB
  __shared__ float sBn[320];
  __shared__ int s_t[160], s_p[160], s_n[16];
  __shared__ unsigned s_am[160];
  __shared__ float s_df[16][28];
  __shared__ float s_hd[16][16];
  __shared__ float s_hd2[16][8];

  const int tid  = threadIdx.x;
  const int b0   = blockIdx.x * BT;
  const int w    = tid >> 6;
  const int lane = tid & 63;

  if (tid < 16) {
    int n = vcount[b0 + tid];
    s_n[tid] = n < 1 ? 1 : (n > MAXN ? MAXN : n);
    // zero the f16 pad of sHg (read as part of f16x8 in heads)
    sHg[tid * 304 + 301] = (_Float16)0.f;
    sHg[tid * 304 + 302] = (_Float16)0.f;
    sHg[tid * 304 + 303] = (_Float16)0.f;
  }
  if (tid < 160) {
    int g = tid / 10, vv = tid % 10;
    s_t[tid] = node_type[(b0 + g) * MAXN + vv];
    s_p[tid] = pos[(b0 + g) * MAXN + vv];
  }
  if (tid < 320) sBn[tid] = bnG[tid];
  __syncthreads();
  if (tid < 160) {
    int g = tid / 10, vv = tid % 10;
    unsigned m = 0;
    if (vv < s_n[g]) {
      for (int u = 0; u < vv; ++u)
        if (adj[(b0 + g) * 100 + u * 10 + vv]) m |= (1u << u);
    }
    s_am[tid] = m;
  }
  __syncthreads();

  const int lq4 = (lane >> 4) << 2;   // base graph row of this lane's D rows
  const int jc  = lane & 15;          // column-within-tile

  for (int v = 0; v < MAXN; ++v) {
    // ---------- phase A (waves 0-10): build GRU A-frags; (waves 11+): gate one-hots ----------
    if (tid < KT1 * 64) {              // 704 threads = waves 0..10 exactly
      int c = tid;
      int kt = c >> 6, ln = c & 63, g = ln & 15;
      int k0 = (kt << 5) + ((ln >> 4) << 3);
      unsigned am = s_am[g * 10 + v];
      f16x8 pk;
      if (k0 + 8 <= HS) {               // pure Hin chunk
        float acc[8];
        #pragma unroll
        for (int e = 0; e < 8; ++e) acc[e] = 0.f;
        for (int u = 0; u < v; ++u) {
          float mf = (float)((am >> u) & 1u);
          f16x8 hh = *(const f16x8*)(sGhist + (u * 16 + g) * 304 + k0);
          #pragma unroll
          for (int e = 0; e < 8; ++e) acc[e] += mf * (float)hh[e];
        }
        #pragma unroll
        for (int e = 0; e < 8; ++e) pk[e] = (_Float16)acc[e];
      } else {                          // boundary / one-hot region
        int t = s_t[g * 10 + v], p = s_p[g * 10 + v];
        #pragma unroll
        for (int e = 0; e < 8; ++e) {
          int k = k0 + e;
          float x = 0.f;
          if (k < HS) {
            for (int u = 0; u < v; ++u)
              if ((am >> u) & 1u) x += (float)sGhist[(u * 16 + g) * 304 + k];
          } else if (k < 327) x = (k - 301 == t) ? 1.f : 0.f;
          else if (k < 336)   x = (k - 327 == p) ? 1.f : 0.f;
          else if (k == 336)  x = 1.f;
          pk[e] = (_Float16)x;
        }
      }
      *(f16x8*)(sAf1 + c * 16) = pk;
    } else if (tid - KT1 * 64 < 16 * 19) {  // gate A-frag one-hot region k=301..319
      int i = tid - KT1 * 64;
      int g = i / 19, kk = 301 + i % 19;
      float val = (kk < 310) ? ((kk - 301 == s_p[g * 10 + v]) ? 1.f : 0.f)
                             : ((kk == 310) ? 1.f : 0.f);
      *(_Float16*)(sAf2 + fragOff(g, kk)) = (_Float16)val;
    }
    __syncthreads();

    // ---------- GRU GEMM, jt-outer: wave w owns j-tiles {w, w+16} ----------
    for (int jj = w; jj < NJT; jj += 16) {
      f32x4 a0 = {0.f,0.f,0.f,0.f}, a1 = {0.f,0.f,0.f,0.f}, a2 = {0.f,0.f,0.f,0.f};
      #pragma unroll
      for (int kt = 0; kt < KT1; ++kt) {
        f16x8 av = *(const f16x8*)(sAf1 + kt * 1024 + lane * 16);
        int base = ((jj * KT1 + kt) * 3) * 64 + lane;
        f16x8 b0v = __builtin_bit_cast(f16x8, B1[base]);
        f16x8 b1v = __builtin_bit_cast(f16x8, B1[base + 64]);
        f16x8 b2v = __builtin_bit_cast(f16x8, B1[base + 128]);
        a0 = __builtin_amdgcn_mfma_f32_16x16x32_f16(av, b0v, a0, 0, 0, 0);
        a1 = __builtin_amdgcn_mfma_f32_16x16x32_f16(av, b1v, a1, 0, 0, 0);
        a2 = __builtin_amdgcn_mfma_f32_16x16x32_f16(av, b2v, a2, 0, 0, 0);
      }
      // epilogue (D: row=graph=(lane>>4)*4+q, col=j=lane&15)
      int j = jj * 16 + jc;
      bool jv = j < HS;
      #pragma unroll
      for (int q = 0; q < 4; ++q) {
        int g = lq4 + q;
        float inn = 0.f;
        if (jv) {
          int t = s_t[g * 10 + v], p = s_p[g * 10 + v];
          inn = sBn[j] + WnX[t * 320 + j] + WnX[(26 + p) * 320 + j];
        }
        float rg = sigm(a0[q]);
        float zg = sigm(a1[q]);
        float ng = tanhf(inn + rg * a2[q]);
        float hinv = jv ? (float)*(const _Float16*)(sAf1 + fragOff(g, j)) : 0.f;
        float hv = (1.f - zg) * ng + zg * hinv;
        float hval = (v < s_n[g]) ? hv : 0.f;
        if (jv) {
          *(_Float16*)(sAf2 + fragOff(g, j)) = (_Float16)hval;
          if (v == s_n[g] - 1) sHg[g * 304 + j] = (_Float16)hv;
        }
      }
    }
    __syncthreads();

    // ---------- gate/mapper GEMM, jt-outer ----------
    if (v < 9) {   // gated[9] never consumed
      for (int jj = w; jj < NJT; jj += 16) {
        f32x4 c0 = {0.f,0.f,0.f,0.f}, c1 = {0.f,0.f,0.f,0.f};
        #pragma unroll
        for (int kt = 0; kt < KT2; ++kt) {
          f16x8 av = *(const f16x8*)(sAf2 + kt * 1024 + lane * 16);
          int base = ((jj * KT2 + kt) * 2) * 64 + lane;
          f16x8 b0v = __builtin_bit_cast(f16x8, B2[base]);
          f16x8 b1v = __builtin_bit_cast(f16x8, B2[base + 64]);
          c0 = __builtin_amdgcn_mfma_f32_16x16x32_f16(av, b0v, c0, 0, 0, 0);
          c1 = __builtin_amdgcn_mfma_f32_16x16x32_f16(av, b1v, c1, 0, 0, 0);
        }
        int j = jj * 16 + jc;
        if (j < HS) {
          #pragma unroll
          for (int q = 0; q < 4; ++q) {
            int g = lq4 + q;
            float gg = sigm(c0[q]);
            sGhist[(v * 16 + g) * 304 + j] = (_Float16)(gg * c1[q]);
          }
        }
      }
    }
    __syncthreads();
  }

  // ---------- df feature ----------
  if (tid < 16) {
    int g = tid;
    #pragma unroll
    for (int i2 = 0; i2 < 27; ++i2) s_df[g][i2] = 0.f;
    int n = s_n[g];
    for (int vv = 0; vv < n; ++vv) {
      int p = s_p[g * 10 + vv];
      int base = (b0 + g) * MAXN + vv;
      s_df[g][3 * p]     = rin[base];
      s_df[g][3 * p + 1] = cin[base];
      s_df[g][3 * p + 2] = gmin[base];
    }
  }
  __syncthreads();

  // ---------- df_enc ----------
  if (tid < 256) {
    int bb = tid >> 4, o = tid & 15;   // 16x16
    float a = b1[o];
    #pragma unroll
    for (int k = 0; k < 27; ++k) a = fmaf(W1[o * 27 + k], s_df[bb][k], a);
    s_hd[bb][o] = fmaxf(a, 0.f);
  }
  __syncthreads();
  if (tid < 128) {
    int bb = tid >> 3, o = tid & 7;
    float a = b2[o];
    #pragma unroll
    for (int k = 0; k < 16; ++k) a = fmaf(W2[o * 16 + k], s_hd[bb][k], a);
    s_hd2[bb][o] = a;
  }
  __syncthreads();

  // ---------- heads ----------
  if (tid < 2 * NZ) {
    bool ismu = tid < NZ;
    int oo = ismu ? tid : tid - NZ;
    const float* WT = ismu ? WmuT : WlvT;
    float acc[16];
    #pragma unroll
    for (int g = 0; g < 16; ++g) acc[g] = 0.f;
    for (int k0 = 0; k0 < 304; k0 += 8) {
      float wv[8];
      #pragma unroll
      for (int e = 0; e < 8; ++e) {
        int k = k0 + e;
        wv[e] = (k < HS) ? WT[k * NZ + oo] : 0.f;
      }
      #pragma unroll
      for (int g = 0; g < 16; ++g) {
        f16x8 hh = *(const f16x8*)(sHg + g * 304 + k0);
        #pragma unroll
        for (int e = 0; e < 8; ++e) acc[g] += wv[e] * (float)hh[e];
      }
    }
    #pragma unroll
    for (int g = 0; g < 16; ++g) {
      float a = acc[g];
      #pragma unroll
      for (int kk = 0; kk < 8; ++kk) a += WT[(HS + kk) * NZ + oo] * s_hd2[g][kk];
      a += ismu ? bmu[oo] : blv[oo];
      out[(ismu ? 0 : BSZ * NZ) + (b0 + g) * NZ + oo] = a;
    }
  }
}

extern "C" void kernel_launch(void* const* d_in, const int* in_sizes, int n_in,
                              void* d_out, int out_size, void* d_ws, size_t ws_size,
                              hipStream_t stream) {
  const int*   node_type = (const int*)d_in[0];
  const int*   pos       = (const int*)d_in[1];
  const int*   adj       = (const int*)d_in[2];
  const int*   vcount    = (const int*)d_in[3];
  const float* rin       = (const float*)d_in[4];
  const float* cin       = (const float*)d_in[5];
  const float* gmin      = (const float*)d_in[6];
  const float* Wih       = (const float*)d_in[7];
  const float* Whh       = (const float*)d_in[8];
  const float* b_ih      = (const float*)d_in[9];
  const float* b_hh      = (const float*)d_in[10];
  const float* Wg        = (const float*)d_in[11];
  const float* bg        = (const float*)d_in[12];
  const float* Wm        = (const float*)d_in[13];
  const float* W1        = (const float*)d_in[14];
  const float* b1        = (const float*)d_in[15];
  const float* W2        = (const float*)d_in[16];
  const float* b2        = (const float*)d_in[17];
  const float* Wmu       = (const float*)d_in[18];
  const float* bmu       = (const float*)d_in[19];
  const float* Wlv       = (const float*)d_in[20];
  const float* blv       = (const float*)d_in[21];

  // ws layout (bytes, all 16B-aligned)
  char* wsb = (char*)d_ws;
  unsigned short* B1 = (unsigned short*)wsb;              // 642,048 B
  unsigned short* B2 = (unsigned short*)(wsb + 642048);   // 389,120 B
  float* WnX  = (float*)(wsb + 1031168);                  // 44,800 B
  float* bn   = (float*)(wsb + 1075968);                  // 1,280 B
  float* WmuT = (float*)(wsb + 1077248);                  // 69,216 B
  float* WlvT = (float*)(wsb + 1146464);                  // 69,216 B

  ckt_prep<<<512, 256, 0, stream>>>(Wih, Whh, b_ih, b_hh, Wg, bg, Wm, Wmu, Wlv,
                                    B1, B2, WnX, bn, WmuT, WlvT);

  ckt_main<<<BSZ / BT, NTH, 0, stream>>>(node_type, pos, adj, vcount, rin, cin, gmin,
      W1, b1, W2, b2, bmu, blv,
      (const uint4*)B1, (const uint4*)B2, WnX, bn, WmuT, WlvT, (float*)d_out);
}

// Round 6
// 230.141 us; speedup vs baseline: 8.0076x; 1.0722x over previous
//
#include <hip/hip_runtime.h>
#include <hip/hip_bf16.h>

// CktGNN encoder via MFMA. R6: depth-sorted groups + 2 blocks/CU overlap.
//   - counting-sort graphs by n (E[n]=4.6 vs 10) -> v-loop runs to block max n
//   - BT=8 graphs/block, 512 blocks, NTH=512 (8 waves), LDS ~72 KB -> 2 blk/CU
//   - snake mapping grp = b<256 ? b : 767-b pairs light+heavy groups per CU
//   - fast tanh (exp-based) in GRU epilogue
// Weights in exact mfma_f32_16x16x32_f16 B-fragment order (L2-resident ~1MB).
//   GRU ext K=352: [Hin(301) | onehot_t(26) | onehot_p(9) | 1 | pad]
//   gate ext K=320: [H(301) | onehot_p(9) | 1 | pad]

#define HS 301
#define NVT 26
#define MAXPOS 9
#define MAXN 10
#define BSZ 4096
#define VS 310
#define GS 309
#define NZ 56

#define KT1 11          // GRU ext K tiles (K=352)
#define KT2 10          // gate ext K tiles (K=320)
#define NJT 19          // j tiles (ceil(301/16), covers j<304)
#define NB1 (NJT*KT1*3*512)   // f16 count
#define NB2 (NJT*KT2*2*512)   // f16 count

typedef _Float16 f16x8 __attribute__((ext_vector_type(8)));
typedef float f32x4 __attribute__((ext_vector_type(4)));

constexpr int NTH  = 512;
constexpr int BT   = 8;
constexpr int NBLK = 512;

__device__ __forceinline__ int fragOff(int g, int k) {
  // byte offset of element (row g, dim k) inside an A-fragment buffer
  return ((k >> 5) << 10) + ((((k & 31) >> 3) << 4) + g) * 16 + ((k & 7) << 1);
}
__device__ __forceinline__ float sigm(float x) { return 1.0f / (1.0f + __expf(-x)); }
__device__ __forceinline__ float tanh_fast(float x) {
  // 1 - 2/(e^2x+1); saturates correctly for |x| large (inf -> 1, 0 -> -1)
  float e = __expf(2.0f * x);
  return 1.0f - 2.0f / (e + 1.0f);
}

// ---------------- sort: counting sort graphs by depth n ----------------
__global__ void ckt_sort(const int* __restrict__ vcount, int* __restrict__ order) {
  __shared__ int cnt[12], off[12];
  int tid = threadIdx.x;
  if (tid < 12) cnt[tid] = 0;
  __syncthreads();
  for (int g = tid; g < BSZ; g += 1024) {
    int n = vcount[g]; n = n < 1 ? 1 : (n > MAXN ? MAXN : n);
    atomicAdd(&cnt[n], 1);
  }
  __syncthreads();
  if (tid == 0) {
    int s = 0;
    for (int i = 1; i <= MAXN; ++i) { off[i] = s; s += cnt[i]; }
  }
  __syncthreads();
  for (int g = tid; g < BSZ; g += 1024) {
    int n = vcount[g]; n = n < 1 ? 1 : (n > MAXN ? MAXN : n);
    int p = atomicAdd(&off[n], 1);
    order[p] = g;
  }
}

// ---------------- prep: pack weights into fragment order ----------------
__global__ void ckt_prep(const float* __restrict__ Wih, const float* __restrict__ Whh,
                         const float* __restrict__ b_ih, const float* __restrict__ b_hh,
                         const float* __restrict__ Wg,  const float* __restrict__ bg,
                         const float* __restrict__ Wm,
                         const float* __restrict__ Wmu, const float* __restrict__ Wlv,
                         unsigned short* __restrict__ B1, unsigned short* __restrict__ B2,
                         float* __restrict__ WnX, float* __restrict__ bn,
                         float* __restrict__ WmuT, float* __restrict__ WlvT)
{
  int i0 = blockIdx.x * blockDim.x + threadIdx.x;
  int str = gridDim.x * blockDim.x;
  // B1: [jt][kt][g3][lane][ii]
  for (int i = i0; i < NB1; i += str) {
    int ii = i & 7, lane = (i >> 3) & 63;
    int r = i >> 9;
    int g3 = r % 3; r /= 3;
    int kt = r % KT1; int jt = r / KT1;
    int j = jt * 16 + (lane & 15);
    int k = kt * 32 + ((lane >> 4) << 3) + ii;
    float val = 0.f;
    if (j < HS) {
      int row = g3 * HS + j;
      if (k < HS) val = Whh[row * HS + k];
      else if (k == 336) val = (g3 < 2) ? (b_ih[row] + b_hh[row]) : b_hh[row];
      else if (g3 < 2) {
        if (k < 327)      val = Wih[row * 35 + (k - 301)];
        else if (k < 336) val = Wih[row * 35 + 26 + (k - 327)];
      }
    }
    B1[i] = __builtin_bit_cast(unsigned short, (_Float16)val);
  }
  // B2: [jt][kt][gm][lane][ii]
  for (int i = i0; i < NB2; i += str) {
    int ii = i & 7, lane = (i >> 3) & 63;
    int r = i >> 9;
    int gm = r % 2; r /= 2;
    int kt = r % KT2; int jt = r / KT2;
    int j = jt * 16 + (lane & 15);
    int k = kt * 32 + ((lane >> 4) << 3) + ii;
    float val = 0.f;
    if (j < HS) {
      const float* W = gm ? Wm : Wg;
      if (k < HS)       val = W[j * VS + k];
      else if (k < 310) val = W[j * VS + HS + (k - 301)];
      else if (k == 310) val = gm ? 0.f : bg[j];
    }
    B2[i] = __builtin_bit_cast(unsigned short, (_Float16)val);
  }
  for (int i = i0; i < 35 * 320; i += str) {
    int x = i / 320, j = i % 320;
    WnX[i] = (j < HS) ? Wih[(2 * HS + j) * 35 + x] : 0.f;
  }
  for (int i = i0; i < 320; i += str) bn[i] = (i < HS) ? b_ih[2 * HS + i] : 0.f;
  for (int i = i0; i < GS * NZ; i += str) {
    int k = i / NZ, o = i % NZ;
    WmuT[i] = Wmu[o * GS + k];
    WlvT[i] = Wlv[o * GS + k];
  }
}

// ---------------- main ----------------
__global__ __launch_bounds__(NTH, 4) void ckt_main(
    const int* __restrict__ node_type, const int* __restrict__ pos,
    const int* __restrict__ adj, const int* __restrict__ vcount,
    const float* __restrict__ rin, const float* __restrict__ cin,
    const float* __restrict__ gmin,
    const float* __restrict__ W1, const float* __restrict__ b1,
    const float* __restrict__ W2, const float* __restrict__ b2,
    const float* __restrict__ bmu, const float* __restrict__ blv,
    const uint4* __restrict__ B1, const uint4* __restrict__ B2,
    const float* __restrict__ WnX, const float* __restrict__ bnG,
    const float* __restrict__ WmuT, const float* __restrict__ WlvT,
    const int* __restrict__ order,
    float* __restrict__ out)
{
  __shared__ __align__(16) _Float16 sGhist[9 * 8 * 304]; // gated history, 43.8 KB
  __shared__ __align__(16) char sAf1[KT1 * 1024];        // GRU A-frags, 11 KB
  __shared__ __align__(16) char sAf2[KT2 * 1024];        // gate A-frags, 10 KB
  __shared__ __align__(16) _Float16 sHg[8 * 304];        // graph state, 4.75 KB
  __shared__ float sBn[320];
  __shared__ int s_gi[8];
  __shared__ int s_t[160], s_p[160], s_n[16];
  __shared__ unsigned s_am[160];
  __shared__ int s_nmax;
  __shared__ float s_df[8][28];
  __shared__ float s_hd[8][16];
  __shared__ float s_hd2[8][8];

  const int tid  = threadIdx.x;
  const int grp  = (blockIdx.x < 256) ? (int)blockIdx.x : 767 - (int)blockIdx.x;
  const int b0   = grp * BT;
  const int w    = tid >> 6;          // 0..7
  const int lane = tid & 63;

  if (tid < 8) s_gi[tid] = order[b0 + tid];
  __syncthreads();
  if (tid < 16) {
    int n = 1;
    if (tid < 8) { n = vcount[s_gi[tid]]; n = n < 1 ? 1 : (n > MAXN ? MAXN : n); }
    s_n[tid] = n;
  }
  if (tid < 8) {   // zero the f16 pad of sHg (read as f16x8 in heads)
    sHg[tid * 304 + 301] = (_Float16)0.f;
    sHg[tid * 304 + 302] = (_Float16)0.f;
    sHg[tid * 304 + 303] = (_Float16)0.f;
  }
  if (tid < 160) {
    int g = tid / 10, vv = tid % 10;
    int t = 0, p = 0;
    if (g < 8) {
      t = node_type[s_gi[g] * MAXN + vv];
      p = pos[s_gi[g] * MAXN + vv];
    }
    s_t[tid] = t; s_p[tid] = p;
  }
  if (tid < 320) sBn[tid] = bnG[tid];
  __syncthreads();
  if (tid < 160) {
    int g = tid / 10, vv = tid % 10;
    unsigned m = 0;
    if (g < 8 && vv < s_n[g]) {
      for (int u = 0; u < vv; ++u)
        if (adj[s_gi[g] * 100 + u * 10 + vv]) m |= (1u << u);
    }
    s_am[tid] = m;
  }
  if (tid == 0) {
    int mx = 1;
    for (int g = 0; g < 8; ++g) mx = max(mx, s_n[g]);
    s_nmax = mx;
  }
  __syncthreads();
  const int nmax = s_nmax;

  const int lq4 = (lane >> 4) << 2;   // base graph row of this lane's D rows
  const int jc  = lane & 15;          // column-within-tile

  for (int v = 0; v < nmax; ++v) {
    // ---------- phase A: build GRU A-frags (Hin + one-hots) ----------
    for (int c = tid; c < KT1 * 64; c += NTH) {
      int kt = c >> 6, ln = c & 63, g = ln & 15;
      int k0 = (kt << 5) + ((ln >> 4) << 3);
      unsigned am = s_am[g * 10 + v];   // pads (g>=8) have am=0
      int gg = g & 7;                   // pads alias row 0-7; masked to 0 anyway
      f16x8 pk;
      if (k0 + 8 <= HS) {               // pure Hin chunk
        float acc[8];
        #pragma unroll
        for (int e = 0; e < 8; ++e) acc[e] = 0.f;
        for (int u = 0; u < v; ++u) {
          float mf = (float)((am >> u) & 1u);
          f16x8 hh = *(const f16x8*)(sGhist + (u * 8 + gg) * 304 + k0);
          #pragma unroll
          for (int e = 0; e < 8; ++e) acc[e] += mf * (float)hh[e];
        }
        #pragma unroll
        for (int e = 0; e < 8; ++e) pk[e] = (_Float16)acc[e];
      } else {                          // boundary / one-hot region
        int t = s_t[g * 10 + v], p = s_p[g * 10 + v];
        #pragma unroll
        for (int e = 0; e < 8; ++e) {
          int k = k0 + e;
          float x = 0.f;
          if (k < HS) {
            for (int u = 0; u < v; ++u) {
              float mf = (float)((am >> u) & 1u);
              x += mf * (float)sGhist[(u * 8 + gg) * 304 + k];
            }
          } else if (k < 327) x = (k - 301 == t) ? 1.f : 0.f;
          else if (k < 336)   x = (k - 327 == p) ? 1.f : 0.f;
          else if (k == 336)  x = 1.f;
          pk[e] = (_Float16)x;
        }
      }
      *(f16x8*)(sAf1 + c * 16) = pk;
    }
    // gate A-frag one-hot region (k=301..319), 16 rows x 19 k (strided-safe)
    for (int i = tid; i < 16 * 19; i += NTH) {
      int g = i / 19, kk = 301 + i % 19;
      float val = (kk < 310) ? ((kk - 301 == s_p[g * 10 + v]) ? 1.f : 0.f)
                             : ((kk == 310) ? 1.f : 0.f);
      *(_Float16*)(sAf2 + fragOff(g, kk)) = (_Float16)val;
    }
    __syncthreads();

    // ---------- GRU GEMM, jt-outer: wave w owns j-tiles {w, w+8, w+16} ----------
    for (int jj = w; jj < NJT; jj += 8) {
      f32x4 a0 = {0.f,0.f,0.f,0.f}, a1 = {0.f,0.f,0.f,0.f}, a2 = {0.f,0.f,0.f,0.f};
      #pragma unroll
      for (int kt = 0; kt < KT1; ++kt) {
        f16x8 av = *(const f16x8*)(sAf1 + kt * 1024 + lane * 16);
        int base = ((jj * KT1 + kt) * 3) * 64 + lane;
        f16x8 b0v = __builtin_bit_cast(f16x8, B1[base]);
        f16x8 b1v = __builtin_bit_cast(f16x8, B1[base + 64]);
        f16x8 b2v = __builtin_bit_cast(f16x8, B1[base + 128]);
        a0 = __builtin_amdgcn_mfma_f32_16x16x32_f16(av, b0v, a0, 0, 0, 0);
        a1 = __builtin_amdgcn_mfma_f32_16x16x32_f16(av, b1v, a1, 0, 0, 0);
        a2 = __builtin_amdgcn_mfma_f32_16x16x32_f16(av, b2v, a2, 0, 0, 0);
      }
      // epilogue (D: row=graph=(lane>>4)*4+q, col=j=lane&15)
      int j = jj * 16 + jc;
      bool jv = j < HS;
      #pragma unroll
      for (int q = 0; q < 4; ++q) {
        int g = lq4 + q;
        float inn = 0.f;
        if (jv) {
          int t = s_t[g * 10 + v], p = s_p[g * 10 + v];
          inn = sBn[j] + WnX[t * 320 + j] + WnX[(26 + p) * 320 + j];
        }
        float rg = sigm(a0[q]);
        float zg = sigm(a1[q]);
        float ng = tanh_fast(inn + rg * a2[q]);
        float hinv = jv ? (float)*(const _Float16*)(sAf1 + fragOff(g, j)) : 0.f;
        float hv = (1.f - zg) * ng + zg * hinv;
        float hval = (v < s_n[g]) ? hv : 0.f;
        if (jv) {
          *(_Float16*)(sAf2 + fragOff(g, j)) = (_Float16)hval;
          if (g < 8 && v == s_n[g] - 1) sHg[g * 304 + j] = (_Float16)hv;
        }
      }
    }
    __syncthreads();

    // ---------- gate/mapper GEMM, jt-outer (skip when no future vertex) ----------
    if (v < nmax - 1) {
      for (int jj = w; jj < NJT; jj += 8) {
        f32x4 c0 = {0.f,0.f,0.f,0.f}, c1 = {0.f,0.f,0.f,0.f};
        #pragma unroll
        for (int kt = 0; kt < KT2; ++kt) {
          f16x8 av = *(const f16x8*)(sAf2 + kt * 1024 + lane * 16);
          int base = ((jj * KT2 + kt) * 2) * 64 + lane;
          f16x8 b0v = __builtin_bit_cast(f16x8, B2[base]);
          f16x8 b1v = __builtin_bit_cast(f16x8, B2[base + 64]);
          c0 = __builtin_amdgcn_mfma_f32_16x16x32_f16(av, b0v, c0, 0, 0, 0);
          c1 = __builtin_amdgcn_mfma_f32_16x16x32_f16(av, b1v, c1, 0, 0, 0);
        }
        int j = jj * 16 + jc;
        if (j < HS) {
          #pragma unroll
          for (int q = 0; q < 4; ++q) {
            int g = lq4 + q;
            if (g < 8) {
              float gg = sigm(c0[q]);
              sGhist[(v * 8 + g) * 304 + j] = (_Float16)(gg * c1[q]);
            }
          }
        }
      }
    }
    __syncthreads();
  }

  // ---------- df feature ----------
  if (tid < 8) {
    int g = tid;
    #pragma unroll
    for (int i2 = 0; i2 < 27; ++i2) s_df[g][i2] = 0.f;
    int n = s_n[g];
    int gi = s_gi[g];
    for (int vv = 0; vv < n; ++vv) {
      int p = s_p[g * 10 + vv];
      int base = gi * MAXN + vv;
      s_df[g][3 * p]     = rin[base];
      s_df[g][3 * p + 1] = cin[base];
      s_df[g][3 * p + 2] = gmin[base];
    }
  }
  __syncthreads();

  // ---------- df_enc ----------
  if (tid < 128) {
    int bb = tid >> 4, o = tid & 15;   // 8x16
    float a = b1[o];
    #pragma unroll
    for (int k = 0; k < 27; ++k) a = fmaf(W1[o * 27 + k], s_df[bb][k], a);
    s_hd[bb][o] = fmaxf(a, 0.f);
  }
  __syncthreads();
  if (tid < 64) {
    int bb = tid >> 3, o = tid & 7;    // 8x8
    float a = b2[o];
    #pragma unroll
    for (int k = 0; k < 16; ++k) a = fmaf(W2[o * 16 + k], s_hd[bb][k], a);
    s_hd2[bb][o] = a;
  }
  __syncthreads();

  // ---------- heads ----------
  if (tid < 2 * NZ) {
    bool ismu = tid < NZ;
    int oo = ismu ? tid : tid - NZ;
    const float* WT = ismu ? WmuT : WlvT;
    float acc[8];
    #pragma unroll
    for (int g = 0; g < 8; ++g) acc[g] = 0.f;
    for (int k0 = 0; k0 < 304; k0 += 8) {
      float wv[8];
      #pragma unroll
      for (int e = 0; e < 8; ++e) {
        int k = k0 + e;
        wv[e] = (k < HS) ? WT[k * NZ + oo] : 0.f;
      }
      #pragma unroll
      for (int g = 0; g < 8; ++g) {
        f16x8 hh = *(const f16x8*)(sHg + g * 304 + k0);
        #pragma unroll
        for (int e = 0; e < 8; ++e) acc[g] += wv[e] * (float)hh[e];
      }
    }
    #pragma unroll
    for (int g = 0; g < 8; ++g) {
      float a = acc[g];
      #pragma unroll
      for (int kk = 0; kk < 8; ++kk) a += WT[(HS + kk) * NZ + oo] * s_hd2[g][kk];
      a += ismu ? bmu[oo] : blv[oo];
      out[(ismu ? 0 : BSZ * NZ) + s_gi[g] * NZ + oo] = a;
    }
  }
}

extern "C" void kernel_launch(void* const* d_in, const int* in_sizes, int n_in,
                              void* d_out, int out_size, void* d_ws, size_t ws_size,
                              hipStream_t stream) {
  const int*   node_type = (const int*)d_in[0];
  const int*   pos       = (const int*)d_in[1];
  const int*   adj       = (const int*)d_in[2];
  const int*   vcount    = (const int*)d_in[3];
  const float* rin       = (const float*)d_in[4];
  const float* cin       = (const float*)d_in[5];
  const float* gmin      = (const float*)d_in[6];
  const float* Wih       = (const float*)d_in[7];
  const float* Whh       = (const float*)d_in[8];
  const float* b_ih      = (const float*)d_in[9];
  const float* b_hh      = (const float*)d_in[10];
  const float* Wg        = (const float*)d_in[11];
  const float* bg        = (const float*)d_in[12];
  const float* Wm        = (const float*)d_in[13];
  const float* W1        = (const float*)d_in[14];
  const float* b1        = (const float*)d_in[15];
  const float* W2        = (const float*)d_in[16];
  const float* b2        = (const float*)d_in[17];
  const float* Wmu       = (const float*)d_in[18];
  const float* bmu       = (const float*)d_in[19];
  const float* Wlv       = (const float*)d_in[20];
  const float* blv       = (const float*)d_in[21];

  // ws layout (bytes, all 16B-aligned)
  char* wsb = (char*)d_ws;
  unsigned short* B1 = (unsigned short*)wsb;              // 642,048 B
  unsigned short* B2 = (unsigned short*)(wsb + 642048);   // 389,120 B
  float* WnX  = (float*)(wsb + 1031168);                  // 44,800 B
  float* bn   = (float*)(wsb + 1075968);                  // 1,280 B
  float* WmuT = (float*)(wsb + 1077248);                  // 69,216 B
  float* WlvT = (float*)(wsb + 1146464);                  // 69,216 B
  int*   order = (int*)(wsb + 1215680);                   // 16,384 B

  ckt_prep<<<512, 256, 0, stream>>>(Wih, Whh, b_ih, b_hh, Wg, bg, Wm, Wmu, Wlv,
                                    B1, B2, WnX, bn, WmuT, WlvT);
  ckt_sort<<<1, 1024, 0, stream>>>(vcount, order);

  ckt_main<<<NBLK, NTH, 0, stream>>>(node_type, pos, adj, vcount, rin, cin, gmin,
      W1, b1, W2, b2, bmu, blv,
      (const uint4*)B1, (const uint4*)B2, WnX, bn, WmuT, WlvT, order, (float*)d_out);
}